// Round 1
// baseline (402.378 us; speedup 1.0000x reference)
//
#include <hip/hip_runtime.h>
#include <hip/hip_bf16.h>
#include <math.h>

#define D_MODEL 6670
#define D_PAD   6688   // 209*32 : K padding for GEMM1
#define HID     100
#define NPAD    128    // N pad (GEMM1) / K pad (GEMM2)
#define BATCH   32
#define SEQ     256
#define NTOK    8192   // BATCH*SEQ
#define DTILES2 108    // GEMM2 d-tiles of 64
#define DP2     6912   // 108*64
#define NEXP    7
#define TEMPR   8.0f
#define LN_EPS  1e-5f

typedef __attribute__((ext_vector_type(8))) short bf16x8;
typedef __attribute__((ext_vector_type(4))) float f32x4;
typedef __attribute__((ext_vector_type(2))) float f32x2;

__device__ __forceinline__ unsigned short f2bf_rtne(float f) {
    unsigned int u = __float_as_uint(f);
    unsigned int r = u + 0x7FFFu + ((u >> 16) & 1u);
    return (unsigned short)(r >> 16);
}
__device__ __forceinline__ float bf2f(unsigned short h) {
    return __uint_as_float(((unsigned int)h) << 16);
}

// ---------------------------------------------------------------------------
// P1: split W_down / W_up into bf16 hi/lo (padded), and gsum = sum_t G (8th
// slot = sum_t W).  One grid-stride-free pass over a unified index space.
// ---------------------------------------------------------------------------
__global__ void k_prep(const float* __restrict__ Wd, const float* __restrict__ Wu,
                       const float* __restrict__ GA, const float* __restrict__ WA,
                       const float* __restrict__ GC, const float* __restrict__ WC,
                       const float* __restrict__ GE, const float* __restrict__ WE,
                       unsigned short* __restrict__ wdhi, unsigned short* __restrict__ wdlo,
                       unsigned short* __restrict__ uhi, unsigned short* __restrict__ ulo,
                       float* __restrict__ gsum) {
    const long NA = (long)NPAD * D_PAD;      // 856064
    const long NB = (long)DP2 * NPAD;        // 884736
    const long NC = 3L * 8 * D_MODEL;        // 160080
    long i = (long)blockIdx.x * blockDim.x + threadIdx.x;
    if (i < NA) {
        int n = (int)(i / D_PAD), k = (int)(i % D_PAD);
        float v = (n < HID && k < D_MODEL) ? Wd[(long)n * D_MODEL + k] : 0.f;
        unsigned short h = f2bf_rtne(v);
        wdhi[i] = h;
        wdlo[i] = f2bf_rtne(v - bf2f(h));
    } else if (i < NA + NB) {
        long j = i - NA;
        int d = (int)(j >> 7), h = (int)(j & 127);
        float v = (d < D_MODEL && h < HID) ? Wu[(long)d * HID + h] : 0.f;
        unsigned short hh = f2bf_rtne(v);
        uhi[j] = hh;
        ulo[j] = f2bf_rtne(v - bf2f(hh));
    } else if (i < NA + NB + NC) {
        long j = i - NA - NB;
        int k = (int)(j / (8 * D_MODEL));
        int r = (int)(j % (8 * D_MODEL));
        int e = r / D_MODEL, d = r % D_MODEL;
        const float* G = (k == 0) ? GA : ((k == 1) ? GC : GE);
        const float* W = (k == 0) ? WA : ((k == 1) ? WC : WE);
        float s;
        if (e < NEXP) {
            const float* p = G + ((long)e * D_MODEL + d) * 3;
            s = p[0] + p[1] + p[2];
        } else {
            const float* p = W + (long)d * 3;
            s = p[0] + p[1] + p[2];
        }
        gsum[j] = s;
    }
}

// ---------------------------------------------------------------------------
// K1: GEMM1  P[kpart, tok, n] = E[tok, :] . W_down[n, :]  (split-bf16, 3-pass)
// BM=32 tokens, N=128 (padded), K split into 2 halves -> 512 blocks.
// Direct global loads (no LDS, no barriers).
// ---------------------------------------------------------------------------
__global__ __launch_bounds__(256, 2) void k_gemm1(
        const float* __restrict__ E,
        const unsigned short* __restrict__ wdhi,
        const unsigned short* __restrict__ wdlo,
        float* __restrict__ P) {
    const int mtile = blockIdx.x >> 1;
    const int kpart = blockIdx.x & 1;
    const int w  = threadIdx.x >> 6;
    const int l  = threadIdx.x & 63;
    const int lk = l >> 4;   // k-block 0..3
    const int lr = l & 15;   // row/col within fragment
    const int tok0 = mtile * 32;
    const int n0 = w * 32;
    const int kstart = kpart ? 3328 : 0;
    const int nsteps = kpart ? 105 : 104;

    f32x4 zero4 = {0.f, 0.f, 0.f, 0.f};
    f32x4 acc[2][2];
    acc[0][0] = zero4; acc[0][1] = zero4; acc[1][0] = zero4; acc[1][1] = zero4;

    for (int st = 0; st < nsteps; ++st) {
        const int kk = kstart + st * 32;
        const int kb = kk + lk * 8;
        bf16x8 ah[2], al[2];
        #pragma unroll
        for (int mf = 0; mf < 2; ++mf) {
            const int row = tok0 + mf * 16 + lr;
            const float* ep = E + (long)row * D_MODEL;
            float f[8];
            #pragma unroll
            for (int j = 0; j < 4; ++j) {
                int k2 = kb + 2 * j;
                if (k2 > D_MODEL - 2) k2 = D_MODEL - 2;   // clamp (pad cols of Wd are 0)
                f32x2 v = *(const f32x2*)(ep + k2);
                f[2 * j]     = v[0];
                f[2 * j + 1] = v[1];
            }
            #pragma unroll
            for (int j = 0; j < 8; ++j) {
                unsigned short hb = f2bf_rtne(f[j]);
                ah[mf][j] = (short)hb;
                al[mf][j] = (short)f2bf_rtne(f[j] - bf2f(hb));
            }
        }
        #pragma unroll
        for (int nf = 0; nf < 2; ++nf) {
            const int col = n0 + nf * 16 + lr;
            const bf16x8 bh = *(const bf16x8*)(wdhi + (long)col * D_PAD + kb);
            const bf16x8 bl = *(const bf16x8*)(wdlo + (long)col * D_PAD + kb);
            #pragma unroll
            for (int mf = 0; mf < 2; ++mf) {
                acc[mf][nf] = __builtin_amdgcn_mfma_f32_16x16x32_bf16(ah[mf], bh, acc[mf][nf], 0, 0, 0);
                acc[mf][nf] = __builtin_amdgcn_mfma_f32_16x16x32_bf16(al[mf], bh, acc[mf][nf], 0, 0, 0);
                acc[mf][nf] = __builtin_amdgcn_mfma_f32_16x16x32_bf16(ah[mf], bl, acc[mf][nf], 0, 0, 0);
            }
        }
    }
    float* Pk = P + (long)kpart * NTOK * NPAD;
    #pragma unroll
    for (int mf = 0; mf < 2; ++mf)
        #pragma unroll
        for (int nf = 0; nf < 2; ++nf)
            #pragma unroll
            for (int i = 0; i < 4; ++i) {
                const int row = tok0 + mf * 16 + lk * 4 + i;
                const int col = n0 + nf * 16 + lr;
                Pk[(long)row * NPAD + col] = acc[mf][nf][i];
            }
}

// ---------------------------------------------------------------------------
// K1b: reduce K-partials, apply SiLU, emit A (fp32 compact) + Ahi/Alo (padded)
// ---------------------------------------------------------------------------
__global__ void k_silu_split(const float* __restrict__ P, float* __restrict__ A,
                             unsigned short* __restrict__ Ahi,
                             unsigned short* __restrict__ Alo) {
    long i = (long)blockIdx.x * blockDim.x + threadIdx.x;
    if (i >= (long)NTOK * NPAD) return;
    int tok = (int)(i >> 7), h = (int)(i & 127);
    if (h < HID) {
        float x = P[i] + P[(long)NTOK * NPAD + i];
        float a = x / (1.f + expf(-x));
        A[(long)tok * HID + h] = a;
        unsigned short hb = f2bf_rtne(a);
        Ahi[i] = hb;
        Alo[i] = f2bf_rtne(a - bf2f(hb));
    } else {
        Ahi[i] = 0;
        Alo[i] = 0;
    }
}

// ---------------------------------------------------------------------------
// K2a: GEMM2 stats pass (bf16 hi only): per (b,dtile) partial sum_d y, y^2
// per token.  Wave = 64 s x 64 d, 4 k-steps of 32 (K padded to 128).
// ---------------------------------------------------------------------------
__global__ __launch_bounds__(256, 2) void k_gemm2_stats(
        const unsigned short* __restrict__ Ahi,
        const unsigned short* __restrict__ uhi,
        float* __restrict__ Sy, float* __restrict__ Sy2) {
    const int dtile = blockIdx.x, b = blockIdx.y;
    const int w = threadIdx.x >> 6, l = threadIdx.x & 63;
    const int lk = l >> 4, lr = l & 15;
    const int d0 = dtile * 64, s0 = w * 64;

    f32x4 zero4 = {0.f, 0.f, 0.f, 0.f};
    f32x4 acc[4][4];
    #pragma unroll
    for (int a = 0; a < 4; ++a)
        #pragma unroll
        for (int c = 0; c < 4; ++c) acc[a][c] = zero4;

    #pragma unroll
    for (int st = 0; st < 4; ++st) {
        const int kb = st * 32 + lk * 8;
        bf16x8 af[4], bfg[4];
        #pragma unroll
        for (int mf = 0; mf < 4; ++mf)
            af[mf] = *(const bf16x8*)(Ahi + ((long)(b * SEQ + s0 + mf * 16 + lr)) * NPAD + kb);
        #pragma unroll
        for (int nf = 0; nf < 4; ++nf)
            bfg[nf] = *(const bf16x8*)(uhi + ((long)(d0 + nf * 16 + lr)) * NPAD + kb);
        #pragma unroll
        for (int mf = 0; mf < 4; ++mf)
            #pragma unroll
            for (int nf = 0; nf < 4; ++nf)
                acc[mf][nf] = __builtin_amdgcn_mfma_f32_16x16x32_bf16(af[mf], bfg[nf], acc[mf][nf], 0, 0, 0);
    }
    #pragma unroll
    for (int mf = 0; mf < 4; ++mf) {
        #pragma unroll
        for (int i = 0; i < 4; ++i) {
            float sy = 0.f, sy2 = 0.f;
            #pragma unroll
            for (int nf = 0; nf < 4; ++nf) {
                float y = acc[mf][nf][i];
                sy += y;
                sy2 += y * y;
            }
            #pragma unroll
            for (int m = 1; m < 16; m <<= 1) {
                sy  += __shfl_xor(sy,  m, 64);
                sy2 += __shfl_xor(sy2, m, 64);
            }
            if (lr == 0) {
                const int s = s0 + mf * 16 + lk * 4 + i;
                const long t = (long)b * SEQ + s;
                Sy [(long)dtile * NTOK + t] = sy;
                Sy2[(long)dtile * NTOK + t] = sy2;
            }
        }
    }
}

// ---------------------------------------------------------------------------
// K2b: reduce stats partials -> mu, rstd per token
// ---------------------------------------------------------------------------
__global__ void k_muinv(const float* __restrict__ Sy, const float* __restrict__ Sy2,
                        float* __restrict__ mu, float* __restrict__ rstd) {
    int t = blockIdx.x * blockDim.x + threadIdx.x;
    if (t >= NTOK) return;
    float s1 = 0.f, s2 = 0.f;
    for (int dt = 0; dt < DTILES2; ++dt) {
        s1 += Sy [(long)dt * NTOK + t];
        s2 += Sy2[(long)dt * NTOK + t];
    }
    float m = s1 / (float)D_MODEL;
    float v = s2 / (float)D_MODEL - m * m;
    mu[t] = m;
    rstd[t] = rsqrtf(v + LN_EPS);
}

// ---------------------------------------------------------------------------
// K2c: GEMM2 again (bf16 hi) + LN + gamma/beta + max/argmax over s per (b,d)
// ---------------------------------------------------------------------------
__global__ __launch_bounds__(256, 2) void k_gemm2_max(
        const unsigned short* __restrict__ Ahi,
        const unsigned short* __restrict__ uhi,
        const float* __restrict__ mu, const float* __restrict__ rstd,
        const float* __restrict__ gamma, const float* __restrict__ beta,
        float* __restrict__ xg, int* __restrict__ sidx) {
    __shared__ float smu[SEQ], sinv[SEQ];
    __shared__ float wval[4][64];
    __shared__ int   warg[4][64];
    const int dtile = blockIdx.x, b = blockIdx.y;
    const int w = threadIdx.x >> 6, l = threadIdx.x & 63;
    const int lk = l >> 4, lr = l & 15;
    const int d0 = dtile * 64, s0 = w * 64;

    for (int t = threadIdx.x; t < SEQ; t += 256) {
        smu[t]  = mu  [b * SEQ + t];
        sinv[t] = rstd[b * SEQ + t];
    }
    __syncthreads();

    f32x4 zero4 = {0.f, 0.f, 0.f, 0.f};
    f32x4 acc[4][4];
    #pragma unroll
    for (int a = 0; a < 4; ++a)
        #pragma unroll
        for (int c = 0; c < 4; ++c) acc[a][c] = zero4;

    #pragma unroll
    for (int st = 0; st < 4; ++st) {
        const int kb = st * 32 + lk * 8;
        bf16x8 af[4], bfg[4];
        #pragma unroll
        for (int mf = 0; mf < 4; ++mf)
            af[mf] = *(const bf16x8*)(Ahi + ((long)(b * SEQ + s0 + mf * 16 + lr)) * NPAD + kb);
        #pragma unroll
        for (int nf = 0; nf < 4; ++nf)
            bfg[nf] = *(const bf16x8*)(uhi + ((long)(d0 + nf * 16 + lr)) * NPAD + kb);
        #pragma unroll
        for (int mf = 0; mf < 4; ++mf)
            #pragma unroll
            for (int nf = 0; nf < 4; ++nf)
                acc[mf][nf] = __builtin_amdgcn_mfma_f32_16x16x32_bf16(af[mf], bfg[nf], acc[mf][nf], 0, 0, 0);
    }

    float g[4], bt[4];
    #pragma unroll
    for (int nf = 0; nf < 4; ++nf) {
        int d = d0 + nf * 16 + lr;
        g[nf]  = (d < D_MODEL) ? gamma[d] : 0.f;
        bt[nf] = (d < D_MODEL) ? beta[d]  : 0.f;
    }
    #pragma unroll
    for (int nf = 0; nf < 4; ++nf) {
        float bv = -INFINITY;
        int bs = 0;
        #pragma unroll
        for (int mf = 0; mf < 4; ++mf)
            #pragma unroll
            for (int i = 0; i < 4; ++i) {
                const int s = s0 + mf * 16 + lk * 4 + i;
                float z = (acc[mf][nf][i] - smu[s]) * sinv[s] * g[nf] + bt[nf];
                if (z > bv || (z == bv && s < bs)) { bv = z; bs = s; }
            }
        for (int m = 16; m < 64; m <<= 1) {
            float ov = __shfl_xor(bv, m, 64);
            int   os = __shfl_xor(bs, m, 64);
            if (ov > bv || (ov == bv && os < bs)) { bv = ov; bs = os; }
        }
        if (lk == 0) { wval[w][nf * 16 + lr] = bv; warg[w][nf * 16 + lr] = bs; }
    }
    __syncthreads();
    if (threadIdx.x < 64) {
        const int c = threadIdx.x;
        float bv = wval[0][c];
        int bs = warg[0][c];
        for (int ww = 1; ww < 4; ++ww) {
            float v = wval[ww][c];
            int s = warg[ww][c];
            if (v > bv || (v == bv && s < bs)) { bv = v; bs = s; }
        }
        const int d = d0 + c;
        if (d < D_MODEL) {
            xg  [(long)b * D_MODEL + d] = bv;
            sidx[(long)b * D_MODEL + d] = bs;
        }
    }
}

// ---------------------------------------------------------------------------
// K3: exact fp32 re-evaluation of the gate at the argmax token
// ---------------------------------------------------------------------------
__global__ void k_reeval(const float* __restrict__ A, const float* __restrict__ Wu,
                         const int* __restrict__ sidx, const float* __restrict__ mu,
                         const float* __restrict__ rstd, const float* __restrict__ gamma,
                         const float* __restrict__ beta, float* __restrict__ xg) {
    const int d = blockIdx.x * 256 + threadIdx.x;
    const int b = blockIdx.y;
    if (d >= D_MODEL) return;
    const long id = (long)b * D_MODEL + d;
    const int s = sidx[id];
    const int tok = b * SEQ + s;
    const float4* ap = (const float4*)(A + (long)tok * HID);
    const float4* up = (const float4*)(Wu + (long)d * HID);
    float acc = 0.f;
    #pragma unroll
    for (int j = 0; j < 25; ++j) {
        float4 a4 = ap[j], u4 = up[j];
        acc += a4.x * u4.x + a4.y * u4.y + a4.z * u4.z + a4.w * u4.w;
    }
    float z = (acc - mu[tok]) * rstd[tok];
    xg[id] = z * gamma[d] + beta[d];
}

// ---------------------------------------------------------------------------
// K4a: gate scores (8 dots of 6670 per (k,b)) + softmax over 8 -> sm[k,b,0..6]
// ---------------------------------------------------------------------------
__global__ void k_scores(const float* __restrict__ xg, const float* __restrict__ gsum,
                         float* __restrict__ sm) {
    const int k = blockIdx.x, b = blockIdx.y;
    __shared__ float red[8][4];
    float acc[8];
    #pragma unroll
    for (int j = 0; j < 8; ++j) acc[j] = 0.f;
    const float* x  = xg + (long)b * D_MODEL;
    const float* gs = gsum + (long)k * 8 * D_MODEL;
    for (int d = threadIdx.x; d < D_MODEL; d += 256) {
        float xv = x[d];
        #pragma unroll
        for (int j = 0; j < 8; ++j) acc[j] += xv * gs[(long)j * D_MODEL + d];
    }
    const int w = threadIdx.x >> 6, l = threadIdx.x & 63;
    #pragma unroll
    for (int j = 0; j < 8; ++j) {
        float v = acc[j];
        for (int m = 1; m < 64; m <<= 1) v += __shfl_xor(v, m, 64);
        if (l == 0) red[j][w] = v;
    }
    __syncthreads();
    if (threadIdx.x == 0) {
        float logit[8], mx = -INFINITY;
        for (int j = 0; j < 8; ++j) {
            logit[j] = (red[j][0] + red[j][1] + red[j][2] + red[j][3]) / TEMPR;
            mx = fmaxf(mx, logit[j]);
        }
        float e[8], ssum = 0.f;
        for (int j = 0; j < 8; ++j) { e[j] = expf(logit[j] - mx); ssum += e[j]; }
        for (int j = 0; j < NEXP; ++j)
            sm[((long)k * BATCH + b) * NEXP + j] = e[j] / ssum;
    }
}

// ---------------------------------------------------------------------------
// K4b: outputs  out[k][b][e] = sum_j sm_j G_k[j][e] + W_k[e]   (e = d*3+t)
// ---------------------------------------------------------------------------
__global__ void k_out(const float* __restrict__ GA, const float* __restrict__ WA,
                      const float* __restrict__ GC, const float* __restrict__ WC,
                      const float* __restrict__ GE, const float* __restrict__ WE,
                      const float* __restrict__ sm, float* __restrict__ out) {
    const int k = blockIdx.z, b = blockIdx.y;
    const float* G = (k == 0) ? GA : ((k == 1) ? GC : GE);
    const float* W = (k == 0) ? WA : ((k == 1) ? WC : WE);
    __shared__ float s[NEXP];
    if (threadIdx.x < NEXP) s[threadIdx.x] = sm[((long)k * BATCH + b) * NEXP + threadIdx.x];
    __syncthreads();
    const int NE = D_MODEL * 3;  // 20010
    float* o = out + ((long)k * BATCH + b) * NE;
    const int e0 = blockIdx.x * 1024;
    for (int e = e0 + threadIdx.x; e < e0 + 1024 && e < NE; e += 256) {
        float acc = W[e];
        #pragma unroll
        for (int j = 0; j < NEXP; ++j) acc += s[j] * G[(long)j * NE + e];
        o[e] = acc;
    }
}

// ---------------------------------------------------------------------------
extern "C" void kernel_launch(void* const* d_in, const int* in_sizes, int n_in,
                              void* d_out, int out_size, void* d_ws, size_t ws_size,
                              hipStream_t stream) {
    const float* E     = (const float*)d_in[0];
    const float* WA    = (const float*)d_in[1];
    const float* GA    = (const float*)d_in[2];
    const float* WC    = (const float*)d_in[3];
    const float* GC    = (const float*)d_in[4];
    const float* WE    = (const float*)d_in[5];
    const float* GE    = (const float*)d_in[6];
    const float* Wd    = (const float*)d_in[7];
    const float* Wu    = (const float*)d_in[8];
    const float* gamma = (const float*)d_in[9];
    const float* beta  = (const float*)d_in[10];
    float* out = (float*)d_out;

    size_t off = 0;
    char* base = (char*)d_ws;
    auto carve = [&](size_t bytes) -> void* {
        void* p = base + off;
        off += (bytes + 255) & ~(size_t)255;
        return p;
    };
    float*          P    = (float*)carve(2L * NTOK * NPAD * 4);
    float*          A    = (float*)carve((long)NTOK * HID * 4);
    unsigned short* Ahi  = (unsigned short*)carve((long)NTOK * NPAD * 2);
    unsigned short* Alo  = (unsigned short*)carve((long)NTOK * NPAD * 2);
    unsigned short* wdhi = (unsigned short*)carve((long)NPAD * D_PAD * 2);
    unsigned short* wdlo = (unsigned short*)carve((long)NPAD * D_PAD * 2);
    unsigned short* uhi  = (unsigned short*)carve((long)DP2 * NPAD * 2);
    unsigned short* ulo  = (unsigned short*)carve((long)DP2 * NPAD * 2);
    float*          gsum = (float*)carve(3L * 8 * D_MODEL * 4);
    float*          Sy   = (float*)carve((long)DTILES2 * NTOK * 4);
    float*          Sy2  = (float*)carve((long)DTILES2 * NTOK * 4);
    float*          muv  = (float*)carve((long)NTOK * 4);
    float*          rstd = (float*)carve((long)NTOK * 4);
    float*          xg   = (float*)carve((long)BATCH * D_MODEL * 4);
    int*            sidx = (int*)carve((long)BATCH * D_MODEL * 4);
    float*          smw  = (float*)carve(3L * BATCH * NEXP * 4);
    (void)ws_size; (void)in_sizes; (void)n_in; (void)out_size;

    {   // prep: 856064 + 884736 + 160080 = 1,900,880 items
        long total = (long)NPAD * D_PAD + (long)DP2 * NPAD + 3L * 8 * D_MODEL;
        int blocks = (int)((total + 255) / 256);
        k_prep<<<blocks, 256, 0, stream>>>(Wd, Wu, GA, WA, GC, WC, GE, WE,
                                           wdhi, wdlo, uhi, ulo, gsum);
    }
    k_gemm1<<<512, 256, 0, stream>>>(E, wdhi, wdlo, P);
    k_silu_split<<<(NTOK * NPAD) / 256, 256, 0, stream>>>(P, A, Ahi, Alo);
    k_gemm2_stats<<<dim3(DTILES2, BATCH), 256, 0, stream>>>(Ahi, uhi, Sy, Sy2);
    k_muinv<<<NTOK / 256, 256, 0, stream>>>(Sy, Sy2, muv, rstd);
    k_gemm2_max<<<dim3(DTILES2, BATCH), 256, 0, stream>>>(Ahi, uhi, muv, rstd,
                                                          gamma, beta, xg, sidx);
    k_reeval<<<dim3(27, BATCH), 256, 0, stream>>>(A, Wu, sidx, muv, rstd,
                                                  gamma, beta, xg);
    k_scores<<<dim3(3, BATCH), 256, 0, stream>>>(xg, gsum, smw);
    k_out<<<dim3(20, BATCH, 3), 256, 0, stream>>>(GA, WA, GC, WC, GE, WE, smw, out);
}

// Round 2
// 312.475 us; speedup vs baseline: 1.2877x; 1.2877x over previous
//
#include <hip/hip_runtime.h>
#include <hip/hip_bf16.h>
#include <math.h>

#define D_MODEL 6670
#define D_PAD   6720   // 105*64 : K padding for GEMM1
#define HID     100
#define NPAD    128    // N pad (GEMM1) / K pad (GEMM2)
#define BATCH   32
#define SEQ     256
#define NTOK    8192   // BATCH*SEQ
#define DTILES2 108    // GEMM2 d-tiles of 64
#define DP2     6912   // 108*64
#define NEXP    7
#define TEMPR   8.0f
#define LN_EPS  1e-5f
#define KPARTS  4      // GEMM1 K-split: steps 26,26,26,27 of BK=64

typedef __attribute__((ext_vector_type(8))) short bf16x8;
typedef __attribute__((ext_vector_type(4))) float f32x4;
typedef __attribute__((ext_vector_type(2))) float f32x2;

__device__ __forceinline__ unsigned short bf_bits(__hip_bfloat16 h) {
    return *reinterpret_cast<unsigned short*>(&h);
}
__device__ __forceinline__ void split_bf(float f, unsigned short& hi, unsigned short& lo) {
    __hip_bfloat16 h = __float2bfloat16(f);          // RTNE, compiler emits cvt_pk
    hi = bf_bits(h);
    float r = f - __bfloat162float(h);
    lo = bf_bits(__float2bfloat16(r));
}

// ---------------------------------------------------------------------------
// P1: split W_down into bf16 hi/lo (padded to [NPAD][D_PAD]); uhi (padded
// [DP2][NPAD]); gsum = sum_t over G/W (8 slots x 3 gates).
// ---------------------------------------------------------------------------
__global__ void k_prep(const float* __restrict__ Wd, const float* __restrict__ Wu,
                       const float* __restrict__ GA, const float* __restrict__ WA,
                       const float* __restrict__ GC, const float* __restrict__ WC,
                       const float* __restrict__ GE, const float* __restrict__ WE,
                       unsigned short* __restrict__ wdhi, unsigned short* __restrict__ wdlo,
                       unsigned short* __restrict__ uhi,
                       float* __restrict__ gsum) {
    const long NA = (long)NPAD * D_PAD;      // 860160
    const long NB = (long)DP2 * NPAD;        // 884736
    const long NC = 3L * 8 * D_MODEL;        // 160080
    long i = (long)blockIdx.x * blockDim.x + threadIdx.x;
    if (i < NA) {
        int n = (int)(i / D_PAD), k = (int)(i % D_PAD);
        float v = (n < HID && k < D_MODEL) ? Wd[(long)n * D_MODEL + k] : 0.f;
        unsigned short h, l;
        split_bf(v, h, l);
        wdhi[i] = h;
        wdlo[i] = l;
    } else if (i < NA + NB) {
        long j = i - NA;
        int d = (int)(j >> 7), h = (int)(j & 127);
        float v = (d < D_MODEL && h < HID) ? Wu[(long)d * HID + h] : 0.f;
        uhi[j] = bf_bits(__float2bfloat16(v));
    } else if (i < NA + NB + NC) {
        long j = i - NA - NB;
        int k = (int)(j / (8 * D_MODEL));
        int r = (int)(j % (8 * D_MODEL));
        int e = r / D_MODEL, d = r % D_MODEL;
        const float* G = (k == 0) ? GA : ((k == 1) ? GC : GE);
        const float* W = (k == 0) ? WA : ((k == 1) ? WC : WE);
        float s;
        if (e < NEXP) {
            const float* p = G + ((long)e * D_MODEL + d) * 3;
            s = p[0] + p[1] + p[2];
        } else {
            const float* p = W + (long)d * 3;
            s = p[0] + p[1] + p[2];
        }
        gsum[j] = s;
    }
}

// ---------------------------------------------------------------------------
// K1: GEMM1  P[kp, tok, n] = E[tok,:].W_down[n,:]  (split-bf16, 3-pass MFMA)
// BM=64 tokens, BN=128 (4 waves x 32 cols), BK=64, KPARTS=4 -> 512 blocks.
// E staged through LDS: cooperative load + ONE conversion, double-buffered.
// ---------------------------------------------------------------------------
#define LDS_STRIDE 72   // 64 + 8 bf16 pad: 144B rows, odd multiple of 16B
__global__ __launch_bounds__(256, 2) void k_gemm1(
        const float* __restrict__ E,
        const unsigned short* __restrict__ wdhi,
        const unsigned short* __restrict__ wdlo,
        float* __restrict__ P) {
    __shared__ __align__(16) unsigned short sehi[2][64][LDS_STRIDE];
    __shared__ __align__(16) unsigned short selo[2][64][LDS_STRIDE];

    const int mtile = blockIdx.x >> 2;
    const int kp    = blockIdx.x & 3;
    const int tid = threadIdx.x;
    const int w  = tid >> 6;
    const int l  = tid & 63;
    const int lk = l >> 4;   // k-subblock 0..3
    const int lr = l & 15;   // row/col within fragment
    const int tok0 = mtile * 64;
    const int n0 = w * 32;
    const int step0 = 26 * kp;
    const int nst = (kp == 3) ? 27 : 26;

    // stage-load mapping: thread -> (row, 16-col chunk)
    const int srow = tid >> 2;          // 0..63
    const int sq   = tid & 3;           // 16-float chunk
    const long grow = (long)(tok0 + srow) * D_MODEL;
    const bool lastrow = (tok0 + srow) == (NTOK - 1);

    f32x2 pre[8];

    auto loadE = [&](int st) {
        const int kb = (step0 + st) * 64 + sq * 16;
        #pragma unroll
        for (int j = 0; j < 8; ++j) {
            const int k2 = kb + 2 * j;
            f32x2 v = {0.f, 0.f};
            if (!lastrow || (k2 + 2 <= D_MODEL))
                v = *(const f32x2*)(E + grow + k2);
            pre[j] = v;
        }
    };
    auto writeLDS = [&](int buf) {
        unsigned short hb[16], lb[16];
        #pragma unroll
        for (int j = 0; j < 8; ++j) {
            split_bf(pre[j][0], hb[2 * j], lb[2 * j]);
            split_bf(pre[j][1], hb[2 * j + 1], lb[2 * j + 1]);
        }
        unsigned short* ph = &sehi[buf][srow][sq * 16];
        unsigned short* pl = &selo[buf][srow][sq * 16];
        *(bf16x8*)(ph)     = *(bf16x8*)(hb);
        *(bf16x8*)(ph + 8) = *(bf16x8*)(hb + 8);
        *(bf16x8*)(pl)     = *(bf16x8*)(lb);
        *(bf16x8*)(pl + 8) = *(bf16x8*)(lb + 8);
    };

    f32x4 zero4 = {0.f, 0.f, 0.f, 0.f};
    f32x4 acc[4][2];
    #pragma unroll
    for (int a = 0; a < 4; ++a) { acc[a][0] = zero4; acc[a][1] = zero4; }

    loadE(0);
    writeLDS(0);
    __syncthreads();

    for (int st = 0; st < nst; ++st) {
        const int cur = st & 1;
        if (st + 1 < nst) loadE(st + 1);

        const int kbase = (step0 + st) * 64;
        #pragma unroll
        for (int half = 0; half < 2; ++half) {
            const int colk = half * 32 + lk * 8;
            bf16x8 ah[4], al[4];
            #pragma unroll
            for (int mf = 0; mf < 4; ++mf) {
                ah[mf] = *(const bf16x8*)&sehi[cur][mf * 16 + lr][colk];
                al[mf] = *(const bf16x8*)&selo[cur][mf * 16 + lr][colk];
            }
            #pragma unroll
            for (int nf = 0; nf < 2; ++nf) {
                const long coff = (long)(n0 + nf * 16 + lr) * D_PAD + kbase + colk;
                const bf16x8 bh = *(const bf16x8*)(wdhi + coff);
                const bf16x8 bl = *(const bf16x8*)(wdlo + coff);
                #pragma unroll
                for (int mf = 0; mf < 4; ++mf) {
                    acc[mf][nf] = __builtin_amdgcn_mfma_f32_16x16x32_bf16(ah[mf], bh, acc[mf][nf], 0, 0, 0);
                    acc[mf][nf] = __builtin_amdgcn_mfma_f32_16x16x32_bf16(al[mf], bh, acc[mf][nf], 0, 0, 0);
                    acc[mf][nf] = __builtin_amdgcn_mfma_f32_16x16x32_bf16(ah[mf], bl, acc[mf][nf], 0, 0, 0);
                }
            }
        }
        __syncthreads();
        if (st + 1 < nst) writeLDS((st + 1) & 1);
        __syncthreads();
    }

    float* Pk = P + (long)kp * NTOK * NPAD;
    #pragma unroll
    for (int mf = 0; mf < 4; ++mf)
        #pragma unroll
        for (int nf = 0; nf < 2; ++nf)
            #pragma unroll
            for (int i = 0; i < 4; ++i) {
                const int row = tok0 + mf * 16 + lk * 4 + i;
                const int col = n0 + nf * 16 + lr;
                Pk[(long)row * NPAD + col] = acc[mf][nf][i];
            }
}

// ---------------------------------------------------------------------------
// K1b: reduce K-partials, SiLU, emit A (fp32 compact) + Ahi (bf16 padded)
// ---------------------------------------------------------------------------
__global__ void k_silu_split(const float* __restrict__ P, float* __restrict__ A,
                             unsigned short* __restrict__ Ahi) {
    long i = (long)blockIdx.x * blockDim.x + threadIdx.x;
    if (i >= (long)NTOK * NPAD) return;
    int tok = (int)(i >> 7), h = (int)(i & 127);
    if (h < HID) {
        float x = P[i] + P[(long)NTOK * NPAD + i]
                + P[2L * NTOK * NPAD + i] + P[3L * NTOK * NPAD + i];
        float a = x / (1.f + expf(-x));
        A[(long)tok * HID + h] = a;
        Ahi[i] = bf_bits(__float2bfloat16(a));
    } else {
        Ahi[i] = 0;
    }
}

// ---------------------------------------------------------------------------
// K2a: GEMM2 stats pass (bf16 hi): per (b,dtile) partial sum_d y, y^2 / token
// ---------------------------------------------------------------------------
__global__ __launch_bounds__(256, 2) void k_gemm2_stats(
        const unsigned short* __restrict__ Ahi,
        const unsigned short* __restrict__ uhi,
        float* __restrict__ Sy, float* __restrict__ Sy2) {
    const int dtile = blockIdx.x, b = blockIdx.y;
    const int w = threadIdx.x >> 6, l = threadIdx.x & 63;
    const int lk = l >> 4, lr = l & 15;
    const int d0 = dtile * 64, s0 = w * 64;

    f32x4 zero4 = {0.f, 0.f, 0.f, 0.f};
    f32x4 acc[4][4];
    #pragma unroll
    for (int a = 0; a < 4; ++a)
        #pragma unroll
        for (int c = 0; c < 4; ++c) acc[a][c] = zero4;

    #pragma unroll
    for (int st = 0; st < 4; ++st) {
        const int kb = st * 32 + lk * 8;
        bf16x8 af[4], bfg[4];
        #pragma unroll
        for (int mf = 0; mf < 4; ++mf)
            af[mf] = *(const bf16x8*)(Ahi + ((long)(b * SEQ + s0 + mf * 16 + lr)) * NPAD + kb);
        #pragma unroll
        for (int nf = 0; nf < 4; ++nf)
            bfg[nf] = *(const bf16x8*)(uhi + ((long)(d0 + nf * 16 + lr)) * NPAD + kb);
        #pragma unroll
        for (int mf = 0; mf < 4; ++mf)
            #pragma unroll
            for (int nf = 0; nf < 4; ++nf)
                acc[mf][nf] = __builtin_amdgcn_mfma_f32_16x16x32_bf16(af[mf], bfg[nf], acc[mf][nf], 0, 0, 0);
    }
    #pragma unroll
    for (int mf = 0; mf < 4; ++mf) {
        #pragma unroll
        for (int i = 0; i < 4; ++i) {
            float sy = 0.f, sy2 = 0.f;
            #pragma unroll
            for (int nf = 0; nf < 4; ++nf) {
                float y = acc[mf][nf][i];
                sy += y;
                sy2 += y * y;
            }
            #pragma unroll
            for (int m = 1; m < 16; m <<= 1) {
                sy  += __shfl_xor(sy,  m, 64);
                sy2 += __shfl_xor(sy2, m, 64);
            }
            if (lr == 0) {
                const int s = s0 + mf * 16 + lk * 4 + i;
                const long t = (long)b * SEQ + s;
                Sy [(long)dtile * NTOK + t] = sy;
                Sy2[(long)dtile * NTOK + t] = sy2;
            }
        }
    }
}

// ---------------------------------------------------------------------------
// K2b: reduce stats partials -> mu, rstd per token
// ---------------------------------------------------------------------------
__global__ void k_muinv(const float* __restrict__ Sy, const float* __restrict__ Sy2,
                        float* __restrict__ mu, float* __restrict__ rstd) {
    int t = blockIdx.x * blockDim.x + threadIdx.x;
    if (t >= NTOK) return;
    float s1 = 0.f, s2 = 0.f;
    for (int dt = 0; dt < DTILES2; ++dt) {
        s1 += Sy [(long)dt * NTOK + t];
        s2 += Sy2[(long)dt * NTOK + t];
    }
    float m = s1 / (float)D_MODEL;
    float v = s2 / (float)D_MODEL - m * m;
    mu[t] = m;
    rstd[t] = rsqrtf(v + LN_EPS);
}

// ---------------------------------------------------------------------------
// K2c: GEMM2 (bf16 hi) + LN + top-2 argmax over s per (b,d)
// ---------------------------------------------------------------------------
__global__ __launch_bounds__(256, 2) void k_gemm2_max(
        const unsigned short* __restrict__ Ahi,
        const unsigned short* __restrict__ uhi,
        const float* __restrict__ mu, const float* __restrict__ rstd,
        const float* __restrict__ gamma, const float* __restrict__ beta,
        int* __restrict__ sidx1, int* __restrict__ sidx2) {
    __shared__ float smu[SEQ], sinv[SEQ];
    __shared__ float wv1[4][64], wv2[4][64];
    __shared__ int   ws1[4][64], ws2[4][64];
    const int dtile = blockIdx.x, b = blockIdx.y;
    const int w = threadIdx.x >> 6, l = threadIdx.x & 63;
    const int lk = l >> 4, lr = l & 15;
    const int d0 = dtile * 64, s0 = w * 64;

    for (int t = threadIdx.x; t < SEQ; t += 256) {
        smu[t]  = mu  [b * SEQ + t];
        sinv[t] = rstd[b * SEQ + t];
    }
    __syncthreads();

    f32x4 zero4 = {0.f, 0.f, 0.f, 0.f};
    f32x4 acc[4][4];
    #pragma unroll
    for (int a = 0; a < 4; ++a)
        #pragma unroll
        for (int c = 0; c < 4; ++c) acc[a][c] = zero4;

    #pragma unroll
    for (int st = 0; st < 4; ++st) {
        const int kb = st * 32 + lk * 8;
        bf16x8 af[4], bfg[4];
        #pragma unroll
        for (int mf = 0; mf < 4; ++mf)
            af[mf] = *(const bf16x8*)(Ahi + ((long)(b * SEQ + s0 + mf * 16 + lr)) * NPAD + kb);
        #pragma unroll
        for (int nf = 0; nf < 4; ++nf)
            bfg[nf] = *(const bf16x8*)(uhi + ((long)(d0 + nf * 16 + lr)) * NPAD + kb);
        #pragma unroll
        for (int mf = 0; mf < 4; ++mf)
            #pragma unroll
            for (int nf = 0; nf < 4; ++nf)
                acc[mf][nf] = __builtin_amdgcn_mfma_f32_16x16x32_bf16(af[mf], bfg[nf], acc[mf][nf], 0, 0, 0);
    }

    float g[4];
    #pragma unroll
    for (int nf = 0; nf < 4; ++nf) {
        int d = d0 + nf * 16 + lr;
        g[nf] = (d < D_MODEL) ? gamma[d] : 0.f;   // beta constant over s: argmax-invariant
    }
    #pragma unroll
    for (int nf = 0; nf < 4; ++nf) {
        float v1 = -INFINITY, v2 = -INFINITY;
        int s1i = 0, s2i = 1;
        #pragma unroll
        for (int mf = 0; mf < 4; ++mf)
            #pragma unroll
            for (int i = 0; i < 4; ++i) {
                const int s = s0 + mf * 16 + lk * 4 + i;
                float z = (acc[mf][nf][i] - smu[s]) * sinv[s] * g[nf];
                if (z > v1)      { v2 = v1; s2i = s1i; v1 = z; s1i = s; }
                else if (z > v2) { v2 = z; s2i = s; }
            }
        for (int m = 16; m < 64; m <<= 1) {
            float ov1 = __shfl_xor(v1, m, 64), ov2 = __shfl_xor(v2, m, 64);
            int   os1 = __shfl_xor(s1i, m, 64), os2 = __shfl_xor(s2i, m, 64);
            if (ov1 > v1) {
                float nv2; int ns2;
                if (v1 >= ov2) { nv2 = v1; ns2 = s1i; } else { nv2 = ov2; ns2 = os2; }
                v1 = ov1; s1i = os1; v2 = nv2; s2i = ns2;
            } else {
                if (ov1 >= v2) { v2 = ov1; s2i = os1; }
            }
        }
        if (lk == 0) {
            wv1[w][nf * 16 + lr] = v1; ws1[w][nf * 16 + lr] = s1i;
            wv2[w][nf * 16 + lr] = v2; ws2[w][nf * 16 + lr] = s2i;
        }
    }
    __syncthreads();
    if (threadIdx.x < 64) {
        const int c = threadIdx.x;
        float v1 = wv1[0][c], v2 = wv2[0][c];
        int s1i = ws1[0][c], s2i = ws2[0][c];
        for (int ww = 1; ww < 4; ++ww) {
            float ov1 = wv1[ww][c], ov2 = wv2[ww][c];
            int os1 = ws1[ww][c], os2 = ws2[ww][c];
            if (ov1 > v1) {
                float nv2; int ns2;
                if (v1 >= ov2) { nv2 = v1; ns2 = s1i; } else { nv2 = ov2; ns2 = os2; }
                v1 = ov1; s1i = os1; v2 = nv2; s2i = ns2;
            } else {
                if (ov1 >= v2) { v2 = ov1; s2i = os1; }
            }
        }
        const int d = d0 + c;
        if (d < D_MODEL) {
            sidx1[(long)b * D_MODEL + d] = s1i;
            sidx2[(long)b * D_MODEL + d] = s2i;
        }
    }
}

// ---------------------------------------------------------------------------
// K3: exact fp32 re-eval of the gate at the top-2 argmax tokens, keep the max
// ---------------------------------------------------------------------------
__global__ void k_reeval(const float* __restrict__ A, const float* __restrict__ Wu,
                         const int* __restrict__ sidx1, const int* __restrict__ sidx2,
                         const float* __restrict__ mu, const float* __restrict__ rstd,
                         const float* __restrict__ gamma, const float* __restrict__ beta,
                         float* __restrict__ xg) {
    const int b = blockIdx.x;
    const int d = blockIdx.y * 256 + threadIdx.x;
    if (d >= D_MODEL) return;
    const long id = (long)b * D_MODEL + d;
    const int t1 = b * SEQ + sidx1[id];
    const int t2 = b * SEQ + sidx2[id];
    const float4* a1 = (const float4*)(A + (long)t1 * HID);
    const float4* a2 = (const float4*)(A + (long)t2 * HID);
    const float4* up = (const float4*)(Wu + (long)d * HID);
    float acc1 = 0.f, acc2 = 0.f;
    #pragma unroll
    for (int j = 0; j < 25; ++j) {
        float4 u4 = up[j];
        float4 x1 = a1[j], x2 = a2[j];
        acc1 += x1.x * u4.x + x1.y * u4.y + x1.z * u4.z + x1.w * u4.w;
        acc2 += x2.x * u4.x + x2.y * u4.y + x2.z * u4.z + x2.w * u4.w;
    }
    float gd = gamma[d];
    float z1 = (acc1 - mu[t1]) * rstd[t1] * gd;
    float z2 = (acc2 - mu[t2]) * rstd[t2] * gd;
    xg[id] = fmaxf(z1, z2) + beta[d];
}

// ---------------------------------------------------------------------------
// K4a: gate scores (8 dots of D per (k,b)) + softmax over 8 -> sm[k,b,0..6]
// ---------------------------------------------------------------------------
__global__ void k_scores(const float* __restrict__ xg, const float* __restrict__ gsum,
                         float* __restrict__ sm) {
    const int k = blockIdx.x, b = blockIdx.y;
    __shared__ float red[8][4];
    float acc[8];
    #pragma unroll
    for (int j = 0; j < 8; ++j) acc[j] = 0.f;
    const float* x  = xg + (long)b * D_MODEL;
    const float* gs = gsum + (long)k * 8 * D_MODEL;
    for (int d = threadIdx.x; d < D_MODEL; d += 256) {
        float xv = x[d];
        #pragma unroll
        for (int j = 0; j < 8; ++j) acc[j] += xv * gs[(long)j * D_MODEL + d];
    }
    const int w = threadIdx.x >> 6, l = threadIdx.x & 63;
    #pragma unroll
    for (int j = 0; j < 8; ++j) {
        float v = acc[j];
        for (int m = 1; m < 64; m <<= 1) v += __shfl_xor(v, m, 64);
        if (l == 0) red[j][w] = v;
    }
    __syncthreads();
    if (threadIdx.x == 0) {
        float logit[8], mx = -INFINITY;
        for (int j = 0; j < 8; ++j) {
            logit[j] = (red[j][0] + red[j][1] + red[j][2] + red[j][3]) / TEMPR;
            mx = fmaxf(mx, logit[j]);
        }
        float e[8], ssum = 0.f;
        for (int j = 0; j < 8; ++j) { e[j] = expf(logit[j] - mx); ssum += e[j]; }
        for (int j = 0; j < NEXP; ++j)
            sm[((long)k * BATCH + b) * NEXP + j] = e[j] / ssum;
    }
}

// ---------------------------------------------------------------------------
// K4b: outputs  out[k][b][e] = sum_j sm_j G_k[j][e] + W_k[e]
// ---------------------------------------------------------------------------
__global__ void k_out(const float* __restrict__ GA, const float* __restrict__ WA,
                      const float* __restrict__ GC, const float* __restrict__ WC,
                      const float* __restrict__ GE, const float* __restrict__ WE,
                      const float* __restrict__ sm, float* __restrict__ out) {
    const int k = blockIdx.z, b = blockIdx.y;
    const float* G = (k == 0) ? GA : ((k == 1) ? GC : GE);
    const float* W = (k == 0) ? WA : ((k == 1) ? WC : WE);
    __shared__ float s[NEXP];
    if (threadIdx.x < NEXP) s[threadIdx.x] = sm[((long)k * BATCH + b) * NEXP + threadIdx.x];
    __syncthreads();
    const int NE = D_MODEL * 3;  // 20010
    float* o = out + ((long)k * BATCH + b) * NE;
    const int e0 = blockIdx.x * 1024;
    for (int e = e0 + threadIdx.x; e < e0 + 1024 && e < NE; e += 256) {
        float acc = W[e];
        #pragma unroll
        for (int j = 0; j < NEXP; ++j) acc += s[j] * G[(long)j * NE + e];
        o[e] = acc;
    }
}

// ---------------------------------------------------------------------------
extern "C" void kernel_launch(void* const* d_in, const int* in_sizes, int n_in,
                              void* d_out, int out_size, void* d_ws, size_t ws_size,
                              hipStream_t stream) {
    const float* E     = (const float*)d_in[0];
    const float* WA    = (const float*)d_in[1];
    const float* GA    = (const float*)d_in[2];
    const float* WC    = (const float*)d_in[3];
    const float* GC    = (const float*)d_in[4];
    const float* WE    = (const float*)d_in[5];
    const float* GE    = (const float*)d_in[6];
    const float* Wd    = (const float*)d_in[7];
    const float* Wu    = (const float*)d_in[8];
    const float* gamma = (const float*)d_in[9];
    const float* beta  = (const float*)d_in[10];
    float* out = (float*)d_out;

    size_t off = 0;
    char* base = (char*)d_ws;
    auto carve = [&](size_t bytes) -> void* {
        void* p = base + off;
        off += (bytes + 255) & ~(size_t)255;
        return p;
    };
    float*          P     = (float*)carve((long)KPARTS * NTOK * NPAD * 4);
    float*          A     = (float*)carve((long)NTOK * HID * 4);
    unsigned short* Ahi   = (unsigned short*)carve((long)NTOK * NPAD * 2);
    unsigned short* wdhi  = (unsigned short*)carve((long)NPAD * D_PAD * 2);
    unsigned short* wdlo  = (unsigned short*)carve((long)NPAD * D_PAD * 2);
    unsigned short* uhi   = (unsigned short*)carve((long)DP2 * NPAD * 2);
    float*          gsum  = (float*)carve(3L * 8 * D_MODEL * 4);
    float*          Sy    = (float*)carve((long)DTILES2 * NTOK * 4);
    float*          Sy2   = (float*)carve((long)DTILES2 * NTOK * 4);
    float*          muv   = (float*)carve((long)NTOK * 4);
    float*          rstd  = (float*)carve((long)NTOK * 4);
    float*          xg    = (float*)carve((long)BATCH * D_MODEL * 4);
    int*            sidx1 = (int*)carve((long)BATCH * D_MODEL * 4);
    int*            sidx2 = (int*)carve((long)BATCH * D_MODEL * 4);
    float*          smw   = (float*)carve(3L * BATCH * NEXP * 4);
    (void)ws_size; (void)in_sizes; (void)n_in; (void)out_size;

    {
        long total = (long)NPAD * D_PAD + (long)DP2 * NPAD + 3L * 8 * D_MODEL;
        int blocks = (int)((total + 255) / 256);
        k_prep<<<blocks, 256, 0, stream>>>(Wd, Wu, GA, WA, GC, WC, GE, WE,
                                           wdhi, wdlo, uhi, gsum);
    }
    k_gemm1<<<(NTOK / 64) * KPARTS, 256, 0, stream>>>(E, wdhi, wdlo, P);
    k_silu_split<<<(NTOK * NPAD) / 256, 256, 0, stream>>>(P, A, Ahi);
    k_gemm2_stats<<<dim3(DTILES2, BATCH), 256, 0, stream>>>(Ahi, uhi, Sy, Sy2);
    k_muinv<<<NTOK / 256, 256, 0, stream>>>(Sy, Sy2, muv, rstd);
    k_gemm2_max<<<dim3(DTILES2, BATCH), 256, 0, stream>>>(Ahi, uhi, muv, rstd,
                                                          gamma, beta, sidx1, sidx2);
    k_reeval<<<dim3(BATCH, 27), 256, 0, stream>>>(A, Wu, sidx1, sidx2, muv, rstd,
                                                  gamma, beta, xg);
    k_scores<<<dim3(3, BATCH), 256, 0, stream>>>(xg, gsum, smw);
    k_out<<<dim3(20, BATCH, 3), 256, 0, stream>>>(GA, WA, GC, WC, GE, WE, smw, out);
}